// Round 14
// baseline (1165.524 us; speedup 1.0000x reference)
//
#include <hip/hip_runtime.h>

typedef unsigned short u16;
typedef __bf16 bf16x8_t __attribute__((ext_vector_type(8)));
typedef float f32x4_t __attribute__((ext_vector_type(4)));

__device__ __forceinline__ u16 f2bf(float f) {
  unsigned u = __builtin_bit_cast(unsigned, f);
  u += 0x7FFFu + ((u >> 16) & 1u);  // round-to-nearest-even
  return (u16)(u >> 16);
}
__device__ __forceinline__ float bf2f(u16 h) {
  unsigned u = ((unsigned)h) << 16;
  return __builtin_bit_cast(float, u);
}

typedef __attribute__((address_space(1))) const unsigned gas_u32;
typedef __attribute__((address_space(3))) unsigned las_u32;
__device__ __forceinline__ void gload16(const void* g, void* l) {
  __builtin_amdgcn_global_load_lds((gas_u32*)g, (las_u32*)l, 16, 0, 0);
}

#define SBAR()                                  \
  do {                                          \
    __builtin_amdgcn_sched_barrier(0);          \
    asm volatile("" ::: "memory");              \
    __builtin_amdgcn_s_barrier();               \
    asm volatile("" ::: "memory");              \
    __builtin_amdgcn_sched_barrier(0);          \
  } while (0)
#define VM5() asm volatile("s_waitcnt vmcnt(5)" ::: "memory")
#define VM6() asm volatile("s_waitcnt vmcnt(6)" ::: "memory")
#define VM10() asm volatile("s_waitcnt vmcnt(10)" ::: "memory")
#define VM12() asm volatile("s_waitcnt vmcnt(12)" ::: "memory")

// ---------------- cast weights fp32->bf16: layout [w1; w3; w2; w4] -----------
__global__ __launch_bounds__(256) void cast4_kernel(
    const float* __restrict__ a0, const float* __restrict__ a1,
    const float* __restrict__ a2, const float* __restrict__ a3,
    u16* __restrict__ out) {
  const int z = blockIdx.z;
  const float* a = (z == 0) ? a0 : (z == 1) ? a1 : (z == 2) ? a2 : a3;
  const int i = blockIdx.x * 256 + threadIdx.x;
  out[(size_t)z * 524288 + i] = f2bf(a[i]);
}

// ---------------- concat b1,b3 -> [1024] -------------------------------------
__global__ __launch_bounds__(256) void bcat_kernel(
    const float* __restrict__ b1, const float* __restrict__ b3,
    float* __restrict__ o) {
  const int i = blockIdx.x * 256 + threadIdx.x;
  o[i] = (i < 512) ? b1[i] : b3[i - 512];
}

// ---------------- fp32 [R,C] -> bf16 [C,R] (batched) --------------------------
__global__ __launch_bounds__(256) void cast_transpose_kernel(
    const float* __restrict__ in, u16* __restrict__ out, int R, int C,
    long sIn, long sOut) {
  __shared__ u16 t[32][33];
  const int b = blockIdx.z;
  in += (long)b * sIn;
  out += (long)b * sOut;
  const int c0 = blockIdx.x * 32, r0 = blockIdx.y * 32;
  const int tx = threadIdx.x, ty = threadIdx.y;
#pragma unroll
  for (int i = 0; i < 32; i += 8)
    t[ty + i][tx] = f2bf(in[(long)(r0 + ty + i) * C + c0 + tx]);
  __syncthreads();
#pragma unroll
  for (int i = 0; i < 32; i += 8)
    out[(long)(c0 + ty + i) * R + r0 + tx] = t[tx][ty + i];
}

// ---------------- bf16 [R,C] -> [C,R], 64x64 tiles, u32-packed ---------------
__global__ __launch_bounds__(256) void transpose64(
    const u16* __restrict__ in, u16* __restrict__ out, int R, int C, long sIn,
    long sOut) {
  __shared__ u16 t[64][66];
  const int b = blockIdx.z;
  in += (long)b * sIn;
  out += (long)b * sOut;
  const int c0 = blockIdx.x * 64, r0 = blockIdx.y * 64;
  const int tx = threadIdx.x & 31, ty = threadIdx.x >> 5;
#pragma unroll
  for (int i = 0; i < 64; i += 8) {
    unsigned v = *(const unsigned*)&in[(long)(r0 + ty + i) * C + c0 + 2 * tx];
    t[ty + i][2 * tx] = (u16)v;
    t[ty + i][2 * tx + 1] = (u16)(v >> 16);
  }
  __syncthreads();
#pragma unroll
  for (int i = 0; i < 64; i += 8) {
    unsigned lo = t[2 * tx][ty + i], hi = t[2 * tx + 1][ty + i];
    *(unsigned*)&out[(long)(c0 + ty + i) * R + r0 + 2 * tx] = lo | (hi << 16);
  }
}

// ---------------- shared staging/fragment macros (BK=64 8-phase template) ----
#define STG_A(bufv, h, kt)                                          \
  do {                                                              \
    const char* g_ = Ag + (size_t)(kt) * 128 + (size_t)(h)*AH;      \
    char* d_ = sAd + (bufv)*32768 + (h)*16384;                      \
    gload16(g_, d_);                                                \
    gload16(g_ + AC, d_ + 8192);                                    \
  } while (0)
#define STG_B(bufv, h, kt)                                          \
  do {                                                              \
    const char* g_ = Bg + (size_t)(kt) * 128 + (size_t)(h)*BH;      \
    char* d_ = sBd + (bufv)*32768 + (h)*16384;                      \
    gload16(g_, d_);                                                \
    gload16(g_ + BC, d_ + 8192);                                    \
  } while (0)
#define LOAD_A(bufv, mh)                                                     \
  _Pragma("unroll") for (int m = 0; m < 4; m++) {                            \
    const int lr_ = (mh)*128 + wr * 64 + m * 16 + l15;                       \
    af[m][0] = *(const bf16x8_t*)(lds + (bufv)*32768 + lr_ * 128 + koff0);   \
    af[m][1] =                                                               \
        *(const bf16x8_t*)(lds + (bufv)*32768 + lr_ * 128 + (koff0 ^ 64));   \
  }
#define LOAD_B(bufv, nh)                                                     \
  _Pragma("unroll") for (int n = 0; n < 2; n++) {                            \
    const int lr_ = (nh)*128 + wc * 32 + n * 16 + l15;                       \
    bfr[(nh)*2 + n][0] =                                                     \
        *(const bf16x8_t*)(lds + 65536 + (bufv)*32768 + lr_ * 128 + koff0);  \
    bfr[(nh)*2 + n][1] = *(const bf16x8_t*)(lds + 65536 + (bufv)*32768 +     \
                                            lr_ * 128 + (koff0 ^ 64));       \
  }
#define MMA(mh, nh)                                                          \
  __builtin_amdgcn_s_setprio(1);                                            \
  _Pragma("unroll") for (int m = 0; m < 4; m++)                              \
      _Pragma("unroll") for (int n = 0; n < 2; n++)                          \
          _Pragma("unroll") for (int kk = 0; kk < 2; kk++)                   \
              acc[(mh)*4 + m][(nh)*2 + n] =                                  \
      __builtin_amdgcn_mfma_f32_16x16x32_bf16(                               \
          af[m][kk], bfr[(nh)*2 + n][kk], acc[(mh)*4 + m][(nh)*2 + n], 0, 0, \
          0);                                                                \
  __builtin_amdgcn_s_setprio(0);

// ---------------- gemm8<MODE>: BK=64, 128KB LDS, 1 block/CU (verified) -------
// MODE 2: out = x + w4 @ yrT^T + b4, fp32. K=512.
// MODE 3: y = P' @ gT^T, K=2304; epilogue multiplies by rowinv (stats ptr).
template <int MODE>
__global__ __launch_bounds__(512, 2) void gemm8(
    const u16* __restrict__ A, const u16* __restrict__ B,
    void* __restrict__ C0, const float* __restrict__ bias,
    const float* __restrict__ resid, float* __restrict__ stats) {
  constexpr int LDA_ = (MODE == 3) ? 2304 : 512;
  constexpr int LDB_ = (MODE == 3) ? 2304 : 512;
  constexpr int KK = (MODE == 3) ? 2304 : 512;
  constexpr int NT = KK >> 6;
  constexpr size_t AH = 64ull * LDA_ * 2, AC = 128ull * LDA_ * 2;
  constexpr size_t BH = 32ull * LDB_ * 2, BC = 128ull * LDB_ * 2;

  __shared__ alignas(16) char lds[131072];
  const int tid = threadIdx.x;
  const int w = tid >> 6, l = tid & 63;
  const int wr = w >> 2, wc = w & 3;
  const int l15 = l & 15, lhi = l >> 4;
  const int koff0 = (lhi * 16) ^ ((l & 7) << 4);

  const unsigned gx = gridDim.x, gy = gridDim.y;
  const unsigned nb = gx * gy * gridDim.z;
  unsigned bid = blockIdx.x + gx * (blockIdx.y + gy * blockIdx.z);
  bid = (bid & 7u) * (nb >> 3) + (bid >> 3);
  const unsigned bx = bid % gx;
  const unsigned t1 = bid / gx;
  const unsigned by = t1 % gy;
  const unsigned bz = t1 / gy;
  const int rowbase = by * 256, colbase = bx * 256;

  const u16* Abase;
  const u16* Bbase;
  if constexpr (MODE == 3) {
    Abase = A + (size_t)bz * 5308416;
    Bbase = B + (size_t)bz * 1179648;
  } else {
    Abase = A;
    Bbase = B + (size_t)bz * 1179648;
  }

  const int sub = tid >> 3;
  const int kb = ((tid & 7) * 16) ^ ((sub & 7) << 4);
  const char* Ag = (const char*)(Abase + (size_t)(rowbase + sub) * LDA_) + kb;
  const char* Bg =
      (const char*)(Bbase + (size_t)(colbase + (sub >> 5) * 64 + (sub & 31)) *
                                LDB_) +
      kb;
  char* sAd = lds + w * 1024;
  char* sBd = lds + 65536 + w * 1024;

  f32x4_t acc[8][4] = {};
  bf16x8_t af[4][2], bfr[4][2];

  // prologue: tile0 + tile1, per-tile FIFO order A0,B0,B1,A1
  STG_A(0, 0, 0); STG_B(0, 0, 0);
  STG_B(0, 1, 0); STG_A(0, 1, 0);
  STG_A(1, 0, 1); STG_B(1, 0, 1);
  STG_B(1, 1, 1); STG_A(1, 1, 1);
  VM12();
  SBAR();

  for (int t = 0; t < NT; ++t) {
    const int c = t & 1;
    const int tn2 = (t + 2 < NT) ? t + 2 : NT - 1;
    LOAD_A(c, 0);
    LOAD_B(c, 0);
    SBAR();
    MMA(0, 0);
    VM10();
    SBAR();
    LOAD_B(c, 1);
    STG_A(c, 0, tn2);
    STG_B(c, 0, tn2);
    SBAR();
    MMA(0, 1);
    VM12();
    SBAR();
    LOAD_A(c, 1);
    STG_B(c, 1, tn2);
    SBAR();
    MMA(1, 0);
    SBAR();
    STG_A(c, 1, tn2);
    VM12();
    SBAR();
    MMA(1, 1);
    SBAR();
  }

  if constexpr (MODE == 3) {
    u16* Cp = (u16*)C0 + (size_t)bz * 1179648;
#pragma unroll
    for (int mf = 0; mf < 8; mf++)
#pragma unroll
      for (int r = 0; r < 4; r++) {
        const int row = rowbase + wr * 128 + mf * 16 + lhi * 4 + r;
        const float invs = stats[(size_t)bz * 2304 + row];
#pragma unroll
        for (int nf = 0; nf < 4; nf++) {
          const int col = colbase + wc * 64 + nf * 16 + l15;
          Cp[(size_t)row * 512 + col] = f2bf(acc[mf][nf][r] * invs);
        }
      }
  } else {
    float* Cp = (float*)C0 + (size_t)bz * 2359296;
    const float* rp = resid + (size_t)bz * 2359296;
#pragma unroll
    for (int mf = 0; mf < 8; mf++)
#pragma unroll
      for (int r = 0; r < 4; r++) {
        const int row = rowbase + wr * 128 + mf * 16 + lhi * 4 + r;
        const float bv = bias[row];
#pragma unroll
        for (int nf = 0; nf < 4; nf++) {
          const int col = colbase + wc * 64 + nf * 16 + l15;
          Cp[(size_t)row * 2304 + col] =
              acc[mf][nf][r] + bv + rp[(size_t)row * 2304 + col];
        }
      }
  }
}

// ---------------- gemm4<MODE>: BK=32, 64KB LDS, 2 blocks/CU ------------------
// Half-scale mirror of the verified template. A half h = rows
// {h*64..h*64+63} U {h*64+128..h*64+191} (wave-partition preserved); B half h
// = cols == [h*32, h*32+32) mod 64. Rows are 64B; chunk-XOR swizzle
// ((rh>>1)&3)<<4 both sides -> 2-way banks (free). 1 gload per half; per-tile
// FIFO A0,B0,B1,A1; tile t+2 staged during t; counted waits VM6/VM5/VM6/VM6
// (every drained load >= 6 phases old).
// MODE 0: conv dual-role (as before). MODE 1: att exp epilogue (as before).
#define QSTG_A(bufv, h, kt)                                          \
  gload16(Ag4 + (size_t)(kt)*64 + (size_t)(h)*QAH,                   \
          lds + (bufv)*16384 + (h)*8192 + w * 1024)
#define QSTG_B(bufv, h, kt)                                          \
  gload16(Bg4 + (size_t)(kt)*64 + (size_t)(h)*QBH,                   \
          lds + 32768 + (bufv)*16384 + (h)*8192 + w * 1024)
#define QLOAD_A(bufv, mh)                                                    \
  _Pragma("unroll") for (int m = 0; m < 4; m++) {                            \
    const int lr_ = wr * 64 + m * 16 + l15;                                  \
    af1[m] = *(const bf16x8_t*)(lds + (bufv)*16384 + (mh)*8192 + lr_ * 64 +  \
                                ((lhi * 16) ^ (((lr_ >> 1) & 3) << 4)));     \
  }
#define QLOAD_B(bufv, nh)                                                    \
  _Pragma("unroll") for (int n = 0; n < 2; n++) {                            \
    const int rh_ = wc * 32 + n * 16 + l15;                                  \
    bfr1[(nh)*2 + n] =                                                       \
        *(const bf16x8_t*)(lds + 32768 + (bufv)*16384 + (nh)*8192 +          \
                           rh_ * 64 +                                        \
                           ((lhi * 16) ^ (((rh_ >> 1) & 3) << 4)));          \
  }
#define QMMA(mh, nh)                                                         \
  __builtin_amdgcn_s_setprio(1);                                            \
  _Pragma("unroll") for (int m = 0; m < 4; m++)                              \
      _Pragma("unroll") for (int n = 0; n < 2; n++)                          \
          acc[(mh)*4 + m][(nh)*2 + n] =                                      \
      __builtin_amdgcn_mfma_f32_16x16x32_bf16(                               \
          af1[m], bfr1[(nh)*2 + n], acc[(mh)*4 + m][(nh)*2 + n], 0, 0, 0);   \
  __builtin_amdgcn_s_setprio(0);

template <int MODE>
__global__ __launch_bounds__(512, 4) void gemm4(
    const u16* __restrict__ A, const u16* __restrict__ B,
    void* __restrict__ C0, void* __restrict__ C1, void* __restrict__ C2,
    const u16* __restrict__ W2, const float* __restrict__ bias,
    const float* __restrict__ bias2, float* __restrict__ stats) {
  constexpr int LDA_ = (MODE == 0) ? 1024 : 512;
  constexpr int LDB_ = (MODE == 0) ? 1024 : 512;
  constexpr int KK = (MODE == 0) ? 1024 : 512;
  constexpr int NT = KK >> 5;
  constexpr size_t QAH = 64ull * LDA_ * 2;  // A half-group stride (64 rows)
  constexpr size_t QBH = 32ull * LDB_ * 2;  // B half-group stride (32 cols)

  __shared__ alignas(16) char lds[65536];
  const int tid = threadIdx.x;
  const int w = tid >> 6, l = tid & 63;
  const int wr = w >> 2, wc = w & 3;
  const int l15 = l & 15, lhi = l >> 4;

  unsigned bx, by, bz;
  bool roleB = false;
  if constexpr (MODE == 0) {
    unsigned bid = blockIdx.x;                      // 1D grid, 432 blocks
    unsigned swz = (bid & 7u) * 54u + (bid >> 3);   // XCD chunk = 54
    roleB = (swz >= 288u);
    unsigned s = roleB ? swz - 288u : swz;
    if (roleB) { bx = s % 2u; by = (s / 2u) % 9u; bz = s / 18u; }
    else       { bx = s % 9u; by = (s / 9u) % 4u; bz = s / 36u; }
  } else {
    unsigned bid = blockIdx.x + 9 * (blockIdx.y + 9 * blockIdx.z);  // 648
    bid = (bid & 7u) * 81u + (bid >> 3);            // XCD chunk = 81 = 1 batch
    bx = bid % 9u;
    unsigned t1 = bid / 9u;
    by = t1 % 9u;
    bz = t1 / 9u;
  }
  const int rowbase = by * 256, colbase = bx * 256;

  const u16* Abase;
  const u16* Bbase;
  if constexpr (MODE == 0) {
    Abase = roleB ? (B + (size_t)bz * 2359296) : A;
    Bbase = roleB ? W2 : (B + (size_t)bz * 2359296);
  } else {
    Abase = A + (size_t)bz * 1179648;
    Bbase = B + (size_t)bz * 1179648;
  }

  // staging bases: thread covers LDS row rh = tid>>2 (64B rows), byte
  // (tid&3)*16 XOR chunk-swizzle. A global row' = (rh&63)+(rh>>6)*128 (+h*64
  // per call); B global col' = (rh>>5)*64+(rh&31) (+h*32 per call).
  const int rh4 = tid >> 2;
  const int kb4 = ((tid & 3) * 16) ^ (((rh4 >> 1) & 3) << 4);
  const int arow = (rh4 & 63) + (rh4 >> 6) * 128;
  const int bcol = (rh4 >> 5) * 64 + (rh4 & 31);
  const char* Ag4 =
      (const char*)(Abase + (size_t)(rowbase + arow) * LDA_) + kb4;
  const char* Bg4 =
      (const char*)(Bbase + (size_t)(colbase + bcol) * LDB_) + kb4;

  f32x4_t acc[8][4] = {};
  bf16x8_t af1[4], bfr1[4];

  // prologue: tile0 + tile1, per-tile FIFO A0,B0,B1,A1 (8 loads)
  QSTG_A(0, 0, 0); QSTG_B(0, 0, 0); QSTG_B(0, 1, 0); QSTG_A(0, 1, 0);
  QSTG_A(1, 0, 1); QSTG_B(1, 0, 1); QSTG_B(1, 1, 1); QSTG_A(1, 1, 1);
  VM6();  // A0(0)+B0(0) landed
  SBAR();

  for (int t = 0; t < NT; ++t) {
    const int c = t & 1;
    const int tn2 = (t + 2 < NT) ? t + 2 : NT - 1;
    // ph1: read A0(t)+B0(t)
    QLOAD_A(c, 0);
    QLOAD_B(c, 0);
    SBAR();
    QMMA(0, 0);
    VM5();  // B1(t) landed
    SBAR();
    // ph2: read B1(t); stage A0(t+2)+B0(t+2)
    QLOAD_B(c, 1);
    QSTG_A(c, 0, tn2);
    QSTG_B(c, 0, tn2);
    SBAR();
    QMMA(0, 1);
    VM6();  // A1(t) landed
    SBAR();
    // ph3: read A1(t); stage B1(t+2)
    QLOAD_A(c, 1);
    QSTG_B(c, 1, tn2);
    SBAR();
    QMMA(1, 0);
    SBAR();
    // ph4: stage A1(t+2)
    QSTG_A(c, 1, tn2);
    VM6();  // A0(t+1)+B0(t+1) landed
    SBAR();
    QMMA(1, 1);
    SBAR();
  }

  if constexpr (MODE == 0) {
    if (!roleB) {
      const int rb = rowbase + wr * 128;
      const int which = rb >> 9;  // 0 -> theta, 1 -> g
      u16* Cp = (u16*)(which ? C1 : C0) + (size_t)bz * 1179648;
      const int rowout0 = rb - which * 512;
#pragma unroll
      for (int mf = 0; mf < 8; mf++)
#pragma unroll
        for (int r = 0; r < 4; r++) {
          const int ro = mf * 16 + lhi * 4 + r;
          const float bv = bias[rb + ro];
          const size_t rowo = (size_t)(rowout0 + ro) * 2304;
#pragma unroll
          for (int nf = 0; nf < 4; nf++) {
            const int col = colbase + wc * 64 + nf * 16 + l15;
            Cp[rowo + col] = f2bf(acc[mf][nf][r] + bv);
          }
        }
    } else {
      u16* Cp = (u16*)C2 + (size_t)bz * 1179648;
#pragma unroll
      for (int mf = 0; mf < 8; mf++)
#pragma unroll
        for (int r = 0; r < 4; r++) {
          const size_t rowo =
              (size_t)(rowbase + wr * 128 + mf * 16 + lhi * 4 + r) * 512;
#pragma unroll
          for (int nf = 0; nf < 4; nf++) {
            const int col = colbase + wc * 64 + nf * 16 + l15;
            Cp[rowo + col] = f2bf(acc[mf][nf][r] + bias2[col]);
          }
        }
    }
  } else {
    u16* Cp = (u16*)C0 + (size_t)bz * 5308416;
#pragma unroll
    for (int mf = 0; mf < 8; mf++)
#pragma unroll
      for (int r = 0; r < 4; r++) {
        const int row = rowbase + wr * 128 + mf * 16 + lhi * 4 + r;
        float sm = 0.f;
#pragma unroll
        for (int nf = 0; nf < 4; nf++) {
          const int col = colbase + wc * 64 + nf * 16 + l15;
          const u16 hb = f2bf(__expf(acc[mf][nf][r]));
          Cp[(size_t)row * 2304 + col] = hb;
          sm += bf2f(hb);  // sum of STORED values so S matches P' exactly
        }
#pragma unroll
        for (int mk = 1; mk < 16; mk <<= 1) sm += __shfl_xor(sm, mk);
        if (l15 == 0)
          stats[((size_t)bz * 36 + bx * 4 + wc) * 2304 + row] = sm;
      }
  }
}

// ---------------- reduce per-row partial sums -> 1/S -------------------------
__global__ __launch_bounds__(256) void reduce_sums(
    const float* __restrict__ stats, float* __restrict__ rowinv) {
  const int i = blockIdx.x * 256 + threadIdx.x;  // [0, 18432)
  const int bz = i / 2304, n = i % 2304;
  const float* s = stats + (size_t)bz * 36 * 2304 + n;
  float S = 0.f;
  for (int j = 0; j < 36; j++) S += s[(size_t)j * 2304];
  rowinv[i] = 1.0f / S;
}

extern "C" void kernel_launch(void* const* d_in, const int* in_sizes, int n_in,
                              void* d_out, int out_size, void* d_ws,
                              size_t ws_size, hipStream_t stream) {
  const float* x = (const float*)d_in[0];
  const float* w1 = (const float*)d_in[1];
  const float* b1 = (const float*)d_in[2];
  const float* w2 = (const float*)d_in[3];
  const float* b2 = (const float*)d_in[4];
  const float* w3 = (const float*)d_in[5];
  const float* b3 = (const float*)d_in[6];
  const float* w4 = (const float*)d_in[7];
  const float* b4 = (const float*)d_in[8];
  float* out = (float*)d_out;
  char* ws = (char*)d_ws;

  // ws layout (256 MiB) identical to round 12.
  if (ws_size < 268435456ull) return;
  u16* p_xT = (u16*)(ws);
  u16* p_gn = (u16*)(ws + 37748736);
  float* p_bcat = (float*)(ws + 56623104);
  u16* p_att = (u16*)(ws);
  float* p_stats = (float*)(ws + 84934656);
  float* p_rinv = (float*)(ws + 87588864);
  u16* p_wb = (u16*)(ws + 169869312);
  u16* p_theta = (u16*)(ws + 174063616);
  u16* p_phiT = (u16*)(ws + 192937984);
  u16* p_gT = (u16*)(ws + 211812352);
  u16* p_y = (u16*)(ws + 230686720);
  u16* p_yrT = (u16*)(ws + 249561088);

  // 1) weights -> bf16 as [w1; w3; w2; w4]; bias concat [b1;b3]
  cast4_kernel<<<dim3(2048, 1, 4), 256, 0, stream>>>(w1, w3, w2, w4, p_wb);
  bcat_kernel<<<dim3(4), 256, 0, stream>>>(b1, b3, p_bcat);
  // 2) xT[b] = cast(x[b])^T : [1024,2304] -> [2304,1024]
  cast_transpose_kernel<<<dim3(72, 32, 8), dim3(32, 8), 0, stream>>>(
      x, p_xT, 1024, 2304, 2359296L, 2359296L);
  // 3) conv dual-role (BK=32, 2 blocks/CU): 432 blocks
  gemm4<0><<<dim3(432), 512, 0, stream>>>(
      p_wb, p_xT, p_theta, p_gn, p_phiT, p_wb + 1048576, p_bcat, b2, nullptr);
  // 4) gT[c][m] = (g_flat viewed [2304,512])^T  (must precede att overwrite)
  transpose64<<<dim3(8, 36, 8), 256, 0, stream>>>(p_gn, p_gT, 2304, 512,
                                                  1179648L, 1179648L);
  // 5) att (BK=32, 2 blocks/CU): P' = bf16 exp(theta_v @ phi_v) + partial sums
  gemm4<1><<<dim3(9, 9, 8), 512, 0, stream>>>(
      p_theta, p_phiT, p_att, nullptr, nullptr, nullptr, nullptr, nullptr,
      p_stats);
  // 6) per-row 1/S
  reduce_sums<<<dim3(72), 256, 0, stream>>>(p_stats, p_rinv);
  // 7) y = P' @ g_v * invS : verified BK=64 256^2, 144 blocks
  gemm8<3><<<dim3(2, 9, 8), 512, 0, stream>>>(p_att, p_gT, p_y, nullptr,
                                              nullptr, p_rinv);
  // 8) yrT = (y_flat viewed [512,2304])^T
  transpose64<<<dim3(36, 8, 8), 256, 0, stream>>>(p_y, p_yrT, 512, 2304,
                                                  1179648L, 1179648L);
  // 9) out = x + w4 @ y_r + b4 : verified BK=64 256^2, 288 blocks
  gemm8<2><<<dim3(9, 4, 8), 512, 0, stream>>>(p_wb + 1572864, p_yrT, out, b4,
                                              x, nullptr);
}

// Round 15
// 309.862 us; speedup vs baseline: 3.7614x; 3.7614x over previous
//
#include <hip/hip_runtime.h>

typedef unsigned short u16;
typedef __bf16 bf16x8_t __attribute__((ext_vector_type(8)));
typedef float f32x4_t __attribute__((ext_vector_type(4)));

__device__ __forceinline__ u16 f2bf(float f) {
  unsigned u = __builtin_bit_cast(unsigned, f);
  u += 0x7FFFu + ((u >> 16) & 1u);  // round-to-nearest-even
  return (u16)(u >> 16);
}
__device__ __forceinline__ float bf2f(u16 h) {
  unsigned u = ((unsigned)h) << 16;
  return __builtin_bit_cast(float, u);
}

typedef __attribute__((address_space(1))) const unsigned gas_u32;
typedef __attribute__((address_space(3))) unsigned las_u32;
__device__ __forceinline__ void gload16(const void* g, void* l) {
  __builtin_amdgcn_global_load_lds((gas_u32*)g, (las_u32*)l, 16, 0, 0);
}

#define SBAR()                                  \
  do {                                          \
    __builtin_amdgcn_sched_barrier(0);          \
    asm volatile("" ::: "memory");              \
    __builtin_amdgcn_s_barrier();               \
    asm volatile("" ::: "memory");              \
    __builtin_amdgcn_sched_barrier(0);          \
  } while (0)
#define VM10() asm volatile("s_waitcnt vmcnt(10)" ::: "memory")
#define VM12() asm volatile("s_waitcnt vmcnt(12)" ::: "memory")

// ---------------- cast weights fp32->bf16: layout [w1; w3; w2; w4] -----------
__global__ __launch_bounds__(256) void cast4_kernel(
    const float* __restrict__ a0, const float* __restrict__ a1,
    const float* __restrict__ a2, const float* __restrict__ a3,
    u16* __restrict__ out) {
  const int z = blockIdx.z;
  const float* a = (z == 0) ? a0 : (z == 1) ? a1 : (z == 2) ? a2 : a3;
  const int i = blockIdx.x * 256 + threadIdx.x;
  out[(size_t)z * 524288 + i] = f2bf(a[i]);
}

// ---------------- concat b1,b3 -> [1024] -------------------------------------
__global__ __launch_bounds__(256) void bcat_kernel(
    const float* __restrict__ b1, const float* __restrict__ b3,
    float* __restrict__ o) {
  const int i = blockIdx.x * 256 + threadIdx.x;
  o[i] = (i < 512) ? b1[i] : b3[i - 512];
}

// ---------------- fp32 [R,C] -> bf16 [C,R] (batched) --------------------------
__global__ __launch_bounds__(256) void cast_transpose_kernel(
    const float* __restrict__ in, u16* __restrict__ out, int R, int C,
    long sIn, long sOut) {
  __shared__ u16 t[32][33];
  const int b = blockIdx.z;
  in += (long)b * sIn;
  out += (long)b * sOut;
  const int c0 = blockIdx.x * 32, r0 = blockIdx.y * 32;
  const int tx = threadIdx.x, ty = threadIdx.y;
#pragma unroll
  for (int i = 0; i < 32; i += 8)
    t[ty + i][tx] = f2bf(in[(long)(r0 + ty + i) * C + c0 + tx]);
  __syncthreads();
#pragma unroll
  for (int i = 0; i < 32; i += 8)
    out[(long)(c0 + ty + i) * R + r0 + tx] = t[tx][ty + i];
}

// ---------------- bf16 [R,C] -> [C,R], 64x64 tiles, u32-packed ---------------
__global__ __launch_bounds__(256) void transpose64(
    const u16* __restrict__ in, u16* __restrict__ out, int R, int C, long sIn,
    long sOut) {
  __shared__ u16 t[64][66];
  const int b = blockIdx.z;
  in += (long)b * sIn;
  out += (long)b * sOut;
  const int c0 = blockIdx.x * 64, r0 = blockIdx.y * 64;
  const int tx = threadIdx.x & 31, ty = threadIdx.x >> 5;
#pragma unroll
  for (int i = 0; i < 64; i += 8) {
    unsigned v = *(const unsigned*)&in[(long)(r0 + ty + i) * C + c0 + 2 * tx];
    t[ty + i][2 * tx] = (u16)v;
    t[ty + i][2 * tx + 1] = (u16)(v >> 16);
  }
  __syncthreads();
#pragma unroll
  for (int i = 0; i < 64; i += 8) {
    unsigned lo = t[2 * tx][ty + i], hi = t[2 * tx + 1][ty + i];
    *(unsigned*)&out[(long)(c0 + ty + i) * R + r0 + 2 * tx] = lo | (hi << 16);
  }
}

// ---------------- shared staging/fragment macros (8-phase 256^2 template) ----
#define STG_A(bufv, h, kt)                                          \
  do {                                                              \
    const char* g_ = Ag + (size_t)(kt) * 128 + (size_t)(h)*AH;      \
    char* d_ = sAd + (bufv)*32768 + (h)*16384;                      \
    gload16(g_, d_);                                                \
    gload16(g_ + AC, d_ + 8192);                                    \
  } while (0)
#define STG_B(bufv, h, kt)                                          \
  do {                                                              \
    const char* g_ = Bg + (size_t)(kt) * 128 + (size_t)(h)*BH;      \
    char* d_ = sBd + (bufv)*32768 + (h)*16384;                      \
    gload16(g_, d_);                                                \
    gload16(g_ + BC, d_ + 8192);                                    \
  } while (0)
#define LOAD_A(bufv, mh)                                                     \
  _Pragma("unroll") for (int m = 0; m < 4; m++) {                            \
    const int lr_ = (mh)*128 + wr * 64 + m * 16 + l15;                       \
    af[m][0] = *(const bf16x8_t*)(lds + (bufv)*32768 + lr_ * 128 + koff0);   \
    af[m][1] =                                                               \
        *(const bf16x8_t*)(lds + (bufv)*32768 + lr_ * 128 + (koff0 ^ 64));   \
  }
#define LOAD_B(bufv, nh)                                                     \
  _Pragma("unroll") for (int n = 0; n < 2; n++) {                            \
    const int lr_ = (nh)*128 + wc * 32 + n * 16 + l15;                       \
    bfr[(nh)*2 + n][0] =                                                     \
        *(const bf16x8_t*)(lds + 65536 + (bufv)*32768 + lr_ * 128 + koff0);  \
    bfr[(nh)*2 + n][1] = *(const bf16x8_t*)(lds + 65536 + (bufv)*32768 +     \
                                            lr_ * 128 + (koff0 ^ 64));       \
  }
#define MMA(mh, nh)                                                          \
  __builtin_amdgcn_s_setprio(1);                                            \
  _Pragma("unroll") for (int m = 0; m < 4; m++)                              \
      _Pragma("unroll") for (int n = 0; n < 2; n++)                          \
          _Pragma("unroll") for (int kk = 0; kk < 2; kk++)                   \
              acc[(mh)*4 + m][(nh)*2 + n] =                                  \
      __builtin_amdgcn_mfma_f32_16x16x32_bf16(                               \
          af[m][kk], bfr[(nh)*2 + n][kk], acc[(mh)*4 + m][(nh)*2 + n], 0, 0, \
          0);                                                                \
  __builtin_amdgcn_s_setprio(0);

// ---------------- gemm8<MODE>: 256x256, 8 waves, 8-phase, XOR-swizzled LDS ---
// Deep ledger: tile t+2 staged entirely during tile t, each half one phase
// after its region dies (A0,B0@ph2; B1@ph3; A1@ph4). Per-tile FIFO issue
// order A0,B0,B1,A1 EVERYWHERE (prologue matches loop). Counted waits
// VM12/VM10/VM12 -> every drained load is 6 phases old; never vmcnt<10.
// MODE 0: conv dual-role. roleA (swz<288): [theta;g] = [w1;w3] @ xT^T, bf16,
//         bias rows (bcat), split C0/C1. roleB: phiT = xT @ w2^T, bf16,
//         bias cols (b2) -> C2. K=1024.
// MODE 1: att: writes bf16(exp(score)) (no max-sub; score max ~55 << 88) and
//         per-(row,64col) partial sums of the STORED bf16 values -> stats.
// MODE 2: out = x + w4 @ yrT^T + b4, fp32. K=512.
// MODE 3: y = P' @ gT^T, K=2304; epilogue multiplies by rowinv (stats ptr).
template <int MODE>
__global__ __launch_bounds__(512, 2) void gemm8(
    const u16* __restrict__ A, const u16* __restrict__ B,
    void* __restrict__ C0, void* __restrict__ C1, void* __restrict__ C2,
    const u16* __restrict__ W2, const float* __restrict__ bias,
    const float* __restrict__ bias2, const float* __restrict__ resid,
    float* __restrict__ stats) {
  constexpr int LDA_ = (MODE == 0) ? 1024 : (MODE == 3) ? 2304 : 512;
  constexpr int LDB_ = (MODE == 0) ? 1024 : (MODE == 3) ? 2304 : 512;
  constexpr int KK = (MODE == 0) ? 1024 : (MODE == 3) ? 2304 : 512;
  constexpr int NT = KK >> 6;
  constexpr size_t AH = 64ull * LDA_ * 2, AC = 128ull * LDA_ * 2;
  constexpr size_t BH = 32ull * LDB_ * 2, BC = 128ull * LDB_ * 2;

  __shared__ alignas(16) char lds[131072];
  const int tid = threadIdx.x;
  const int w = tid >> 6, l = tid & 63;
  const int wr = w >> 2, wc = w & 3;
  const int l15 = l & 15, lhi = l >> 4;
  const int koff0 = (lhi * 16) ^ ((l & 7) << 4);

  unsigned bx, by, bz;
  bool roleB = false;
  if constexpr (MODE == 0) {
    unsigned bid = blockIdx.x;                      // 1D grid, 432 blocks
    unsigned swz = (bid & 7u) * 54u + (bid >> 3);   // XCD chunk = 54
    roleB = (swz >= 288u);
    unsigned s = roleB ? swz - 288u : swz;
    if (roleB) { bx = s % 2u; by = (s / 2u) % 9u; bz = s / 18u; }
    else       { bx = s % 9u; by = (s / 9u) % 4u; bz = s / 36u; }
  } else {
    const unsigned gx = gridDim.x, gy = gridDim.y;
    const unsigned nb = gx * gy * gridDim.z;
    unsigned bid = blockIdx.x + gx * (blockIdx.y + gy * blockIdx.z);
    bid = (bid & 7u) * (nb >> 3) + (bid >> 3);
    bx = bid % gx;
    unsigned t1 = bid / gx;
    by = t1 % gy;
    bz = t1 / gy;
  }
  const int rowbase = by * 256, colbase = bx * 256;

  const u16* Abase;
  const u16* Bbase;
  if constexpr (MODE == 0) {
    Abase = roleB ? (B + (size_t)bz * 2359296) : A;
    Bbase = roleB ? W2 : (B + (size_t)bz * 2359296);
  } else if constexpr (MODE == 1) {
    Abase = A + (size_t)bz * 1179648;
    Bbase = B + (size_t)bz * 1179648;
  } else if constexpr (MODE == 3) {
    Abase = A + (size_t)bz * 5308416;
    Bbase = B + (size_t)bz * 1179648;
  } else {
    Abase = A;
    Bbase = B + (size_t)bz * 1179648;
  }

  const int sub = tid >> 3;
  const int kb = ((tid & 7) * 16) ^ ((sub & 7) << 4);
  const char* Ag = (const char*)(Abase + (size_t)(rowbase + sub) * LDA_) + kb;
  const char* Bg =
      (const char*)(Bbase + (size_t)(colbase + (sub >> 5) * 64 + (sub & 31)) *
                                LDB_) +
      kb;
  char* sAd = lds + w * 1024;
  char* sBd = lds + 65536 + w * 1024;

  f32x4_t acc[8][4] = {};
  bf16x8_t af[4][2], bfr[4][2];

  // prologue: tile0 + tile1 fully staged, per-tile FIFO order A0,B0,B1,A1
  STG_A(0, 0, 0); STG_B(0, 0, 0);
  STG_B(0, 1, 0); STG_A(0, 1, 0);
  STG_A(1, 0, 1); STG_B(1, 0, 1);
  STG_B(1, 1, 1); STG_A(1, 1, 1);
  VM12();  // A0(0)+B0(0) landed
  SBAR();

  for (int t = 0; t < NT; ++t) {
    const int c = t & 1;
    const int tn2 = (t + 2 < NT) ? t + 2 : NT - 1;
    // ph1: read A0(t)+B0(t)
    LOAD_A(c, 0);
    LOAD_B(c, 0);
    SBAR();
    MMA(0, 0);
    VM10();  // B1(t) landed (issued 6 phases ago)
    SBAR();
    // ph2: read B1(t); stage A0(t+2)+B0(t+2) into just-dead regions of buf c
    LOAD_B(c, 1);
    STG_A(c, 0, tn2);
    STG_B(c, 0, tn2);
    SBAR();
    MMA(0, 1);
    VM12();  // A1(t) landed (issued 6 phases ago)
    SBAR();
    // ph3: read A1(t); stage B1(t+2)
    LOAD_A(c, 1);
    STG_B(c, 1, tn2);
    SBAR();
    MMA(1, 0);
    SBAR();
    // ph4: stage A1(t+2)
    STG_A(c, 1, tn2);
    VM12();  // A0(t+1)+B0(t+1) landed (issued 6 phases ago)
    SBAR();
    MMA(1, 1);
    SBAR();
  }

  if constexpr (MODE == 0) {
    if (!roleB) {
      const int rb = rowbase + wr * 128;
      const int which = rb >> 9;  // 0 -> theta, 1 -> g
      u16* Cp = (u16*)(which ? C1 : C0) + (size_t)bz * 1179648;
      const int rowout0 = rb - which * 512;
#pragma unroll
      for (int mf = 0; mf < 8; mf++)
#pragma unroll
        for (int r = 0; r < 4; r++) {
          const int ro = mf * 16 + lhi * 4 + r;
          const float bv = bias[rb + ro];
          const size_t rowo = (size_t)(rowout0 + ro) * 2304;
#pragma unroll
          for (int nf = 0; nf < 4; nf++) {
            const int col = colbase + wc * 64 + nf * 16 + l15;
            Cp[rowo + col] = f2bf(acc[mf][nf][r] + bv);
          }
        }
    } else {
      u16* Cp = (u16*)C2 + (size_t)bz * 1179648;
#pragma unroll
      for (int mf = 0; mf < 8; mf++)
#pragma unroll
        for (int r = 0; r < 4; r++) {
          const size_t rowo =
              (size_t)(rowbase + wr * 128 + mf * 16 + lhi * 4 + r) * 512;
#pragma unroll
          for (int nf = 0; nf < 4; nf++) {
            const int col = colbase + wc * 64 + nf * 16 + l15;
            Cp[rowo + col] = f2bf(acc[mf][nf][r] + bias2[col]);
          }
        }
    }
  } else if constexpr (MODE == 1) {
    u16* Cp = (u16*)C0 + (size_t)bz * 5308416;
#pragma unroll
    for (int mf = 0; mf < 8; mf++)
#pragma unroll
      for (int r = 0; r < 4; r++) {
        const int row = rowbase + wr * 128 + mf * 16 + lhi * 4 + r;
        float sm = 0.f;
#pragma unroll
        for (int nf = 0; nf < 4; nf++) {
          const int col = colbase + wc * 64 + nf * 16 + l15;
          const u16 hb = f2bf(__expf(acc[mf][nf][r]));
          Cp[(size_t)row * 2304 + col] = hb;
          sm += bf2f(hb);  // sum of STORED values so S matches P' exactly
        }
#pragma unroll
        for (int mk = 1; mk < 16; mk <<= 1) sm += __shfl_xor(sm, mk);
        if (l15 == 0)
          stats[((size_t)bz * 36 + bx * 4 + wc) * 2304 + row] = sm;
      }
  } else if constexpr (MODE == 3) {
    u16* Cp = (u16*)C0 + (size_t)bz * 1179648;
#pragma unroll
    for (int mf = 0; mf < 8; mf++)
#pragma unroll
      for (int r = 0; r < 4; r++) {
        const int row = rowbase + wr * 128 + mf * 16 + lhi * 4 + r;
        const float invs = stats[(size_t)bz * 2304 + row];
#pragma unroll
        for (int nf = 0; nf < 4; nf++) {
          const int col = colbase + wc * 64 + nf * 16 + l15;
          Cp[(size_t)row * 512 + col] = f2bf(acc[mf][nf][r] * invs);
        }
      }
  } else {
    float* Cp = (float*)C0 + (size_t)bz * 2359296;
    const float* rp = resid + (size_t)bz * 2359296;
#pragma unroll
    for (int mf = 0; mf < 8; mf++)
#pragma unroll
      for (int r = 0; r < 4; r++) {
        const int row = rowbase + wr * 128 + mf * 16 + lhi * 4 + r;
        const float bv = bias[row];
#pragma unroll
        for (int nf = 0; nf < 4; nf++) {
          const int col = colbase + wc * 64 + nf * 16 + l15;
          Cp[(size_t)row * 2304 + col] =
              acc[mf][nf][r] + bv + rp[(size_t)row * 2304 + col];
        }
      }
  }
}

// ---------------- reduce per-row partial sums -> 1/S -------------------------
__global__ __launch_bounds__(256) void reduce_sums(
    const float* __restrict__ stats, float* __restrict__ rowinv) {
  const int i = blockIdx.x * 256 + threadIdx.x;  // [0, 18432)
  const int bz = i / 2304, n = i % 2304;
  const float* s = stats + (size_t)bz * 36 * 2304 + n;
  float S = 0.f;
  for (int j = 0; j < 36; j++) S += s[(size_t)j * 2304];
  rowinv[i] = 1.0f / S;
}

extern "C" void kernel_launch(void* const* d_in, const int* in_sizes, int n_in,
                              void* d_out, int out_size, void* d_ws,
                              size_t ws_size, hipStream_t stream) {
  const float* x = (const float*)d_in[0];
  const float* w1 = (const float*)d_in[1];
  const float* b1 = (const float*)d_in[2];
  const float* w2 = (const float*)d_in[3];
  const float* b2 = (const float*)d_in[4];
  const float* w3 = (const float*)d_in[5];
  const float* b3 = (const float*)d_in[6];
  const float* w4 = (const float*)d_in[7];
  const float* b4 = (const float*)d_in[8];
  float* out = (float*)d_out;
  char* ws = (char*)d_ws;

  // B=8, HW=2304, CIN=1024, CMID=512. ws = 256 MiB:
  //  [0,84.93M)        att P' = bf16 exp(score); before att this window holds
  //                    xT(37.75M) | g_nat(18.87M) | bcat(4K) — all dead then.
  //  [84.93M,87.59M)   partial row sums 8*36*2304 f32 (2.65M)
  //  [87.59M,87.66M)   rowinv 8*2304 f32
  //  [169.87M)         wb 4M | theta | phiT | gT | y | yrT (18.87M each)
  if (ws_size < 268435456ull) return;
  u16* p_xT = (u16*)(ws);
  u16* p_gn = (u16*)(ws + 37748736);
  float* p_bcat = (float*)(ws + 56623104);
  u16* p_att = (u16*)(ws);
  float* p_stats = (float*)(ws + 84934656);
  float* p_rinv = (float*)(ws + 87588864);
  u16* p_wb = (u16*)(ws + 169869312);
  u16* p_theta = (u16*)(ws + 174063616);
  u16* p_phiT = (u16*)(ws + 192937984);
  u16* p_gT = (u16*)(ws + 211812352);
  u16* p_y = (u16*)(ws + 230686720);
  u16* p_yrT = (u16*)(ws + 249561088);

  // 1) weights -> bf16 as [w1; w3; w2; w4]; bias concat [b1;b3]
  cast4_kernel<<<dim3(2048, 1, 4), 256, 0, stream>>>(w1, w3, w2, w4, p_wb);
  bcat_kernel<<<dim3(4), 256, 0, stream>>>(b1, b3, p_bcat);
  // 2) xT[b] = cast(x[b])^T : [1024,2304] -> [2304,1024]
  cast_transpose_kernel<<<dim3(72, 32, 8), dim3(32, 8), 0, stream>>>(
      x, p_xT, 1024, 2304, 2359296L, 2359296L);
  // 3) conv dual-role: 288 blocks [theta;g] + 144 blocks phiT (432 total)
  gemm8<0><<<dim3(432), 512, 0, stream>>>(
      p_wb, p_xT, p_theta, p_gn, p_phiT, p_wb + 1048576, p_bcat, b2, nullptr,
      nullptr);
  // 4) gT[c][m] = (g_flat viewed [2304,512])^T  (must precede att overwrite)
  transpose64<<<dim3(8, 36, 8), 256, 0, stream>>>(p_gn, p_gT, 2304, 512,
                                                  1179648L, 1179648L);
  // 5) att: P' = bf16 exp(theta_v @ phi_v), partial row sums -> stats
  gemm8<1><<<dim3(9, 9, 8), 512, 0, stream>>>(
      p_theta, p_phiT, p_att, nullptr, nullptr, nullptr, nullptr, nullptr,
      nullptr, p_stats);
  // 6) per-row 1/S
  reduce_sums<<<dim3(72), 256, 0, stream>>>(p_stats, p_rinv);
  // 7) y = P' @ g_v * invS : 256^2 tiles, 144 blocks (18/XCD, single round)
  gemm8<3><<<dim3(2, 9, 8), 512, 0, stream>>>(
      p_att, p_gT, p_y, nullptr, nullptr, nullptr, nullptr, nullptr, nullptr,
      p_rinv);
  // 8) yrT = (y_flat viewed [512,2304])^T
  transpose64<<<dim3(36, 8, 8), 256, 0, stream>>>(p_y, p_yrT, 512, 2304,
                                                  1179648L, 1179648L);
  // 9) out = x + w4 @ y_r + b4
  gemm8<2><<<dim3(9, 4, 8), 512, 0, stream>>>(
      p_wb + 1572864, p_yrT, out, nullptr, nullptr, nullptr, b4, nullptr, x,
      nullptr);
}

// Round 16
// 299.436 us; speedup vs baseline: 3.8924x; 1.0348x over previous
//
#include <hip/hip_runtime.h>

typedef unsigned short u16;
typedef __bf16 bf16x8_t __attribute__((ext_vector_type(8)));
typedef float f32x4_t __attribute__((ext_vector_type(4)));

__device__ __forceinline__ u16 f2bf(float f) {
  unsigned u = __builtin_bit_cast(unsigned, f);
  u += 0x7FFFu + ((u >> 16) & 1u);  // round-to-nearest-even
  return (u16)(u >> 16);
}
__device__ __forceinline__ float bf2f(u16 h) {
  unsigned u = ((unsigned)h) << 16;
  return __builtin_bit_cast(float, u);
}

typedef __attribute__((address_space(1))) const unsigned gas_u32;
typedef __attribute__((address_space(3))) unsigned las_u32;
__device__ __forceinline__ void gload16(const void* g, void* l) {
  __builtin_amdgcn_global_load_lds((gas_u32*)g, (las_u32*)l, 16, 0, 0);
}

#define SBAR()                                  \
  do {                                          \
    __builtin_amdgcn_sched_barrier(0);          \
    asm volatile("" ::: "memory");              \
    __builtin_amdgcn_s_barrier();               \
    asm volatile("" ::: "memory");              \
    __builtin_amdgcn_sched_barrier(0);          \
  } while (0)
#define VM0() asm volatile("s_waitcnt vmcnt(0)" ::: "memory")
#define VM10() asm volatile("s_waitcnt vmcnt(10)" ::: "memory")
#define VM12() asm volatile("s_waitcnt vmcnt(12)" ::: "memory")
#define LGKM0() asm volatile("s_waitcnt lgkmcnt(0)" ::: "memory")

// ---------------- fused prep: x castT (18432) | w cast (8192) | bcat (4) ----
__global__ __launch_bounds__(256) void prep_kernel(
    const float* __restrict__ x, const float* __restrict__ w1,
    const float* __restrict__ w3, const float* __restrict__ w2,
    const float* __restrict__ w4, const float* __restrict__ b1,
    const float* __restrict__ b3, u16* __restrict__ xT, u16* __restrict__ wb,
    float* __restrict__ bcat) {
  const unsigned idx = blockIdx.x;
  const int tid = threadIdx.x;
  if (idx < 18432u) {
    // xT[b] = cast(x[b])^T : [1024,2304] -> [2304,1024], 32x32 tiles
    __shared__ u16 t[32][33];
    const int xx = idx % 72, yy = (idx / 72) % 32, b = idx / 2304;
    const float* in = x + (size_t)b * 2359296;
    u16* out = xT + (size_t)b * 2359296;
    const int c0 = xx * 32, r0 = yy * 32;
    const int tx = tid & 31, ty = tid >> 5;
#pragma unroll
    for (int i = 0; i < 32; i += 8)
      t[ty + i][tx] = f2bf(in[(size_t)(r0 + ty + i) * 2304 + c0 + tx]);
    __syncthreads();
#pragma unroll
    for (int i = 0; i < 32; i += 8)
      out[(size_t)(c0 + ty + i) * 1024 + r0 + tx] = t[tx][ty + i];
  } else if (idx < 26624u) {
    // weights -> bf16 as [w1; w3; w2; w4]
    const unsigned k = idx - 18432u;
    const int z = k >> 11;
    const float* a = (z == 0) ? w1 : (z == 1) ? w3 : (z == 2) ? w2 : w4;
    const int i = (int)(k & 2047u) * 256 + tid;
    wb[(size_t)z * 524288 + i] = f2bf(a[i]);
  } else {
    const int i = (int)(idx - 26624u) * 256 + tid;
    if (i < 1024) bcat[i] = (i < 512) ? b1[i] : b3[i - 512];
  }
}

// ---------------- bf16 [R,C] -> [C,R], 64x64 tiles, u32-packed ---------------
__global__ __launch_bounds__(256) void transpose64(
    const u16* __restrict__ in, u16* __restrict__ out, int R, int C, long sIn,
    long sOut) {
  __shared__ u16 t[64][66];
  const int b = blockIdx.z;
  in += (long)b * sIn;
  out += (long)b * sOut;
  const int c0 = blockIdx.x * 64, r0 = blockIdx.y * 64;
  const int tx = threadIdx.x & 31, ty = threadIdx.x >> 5;
#pragma unroll
  for (int i = 0; i < 64; i += 8) {
    unsigned v = *(const unsigned*)&in[(long)(r0 + ty + i) * C + c0 + 2 * tx];
    t[ty + i][2 * tx] = (u16)v;
    t[ty + i][2 * tx + 1] = (u16)(v >> 16);
  }
  __syncthreads();
#pragma unroll
  for (int i = 0; i < 64; i += 8) {
    unsigned lo = t[2 * tx][ty + i], hi = t[2 * tx + 1][ty + i];
    *(unsigned*)&out[(long)(c0 + ty + i) * R + r0 + 2 * tx] = lo | (hi << 16);
  }
}

// ---------------- shared staging/fragment macros (8-phase 256^2 template) ----
#define STG_A(bufv, h, kt)                                          \
  do {                                                              \
    const char* g_ = Ag + (size_t)(kt) * 128 + (size_t)(h)*AH;      \
    char* d_ = sAd + (bufv)*32768 + (h)*16384;                      \
    gload16(g_, d_);                                                \
    gload16(g_ + AC, d_ + 8192);                                    \
  } while (0)
#define STG_B(bufv, h, kt)                                          \
  do {                                                              \
    const char* g_ = Bg + (size_t)(kt) * 128 + (size_t)(h)*BH;      \
    char* d_ = sBd + (bufv)*32768 + (h)*16384;                      \
    gload16(g_, d_);                                                \
    gload16(g_ + BC, d_ + 8192);                                    \
  } while (0)
#define LOAD_A(bufv, mh)                                                     \
  _Pragma("unroll") for (int m = 0; m < 4; m++) {                            \
    const int lr_ = (mh)*128 + wr * 64 + m * 16 + l15;                       \
    af[m][0] = *(const bf16x8_t*)(lds + (bufv)*32768 + lr_ * 128 + koff0);   \
    af[m][1] =                                                               \
        *(const bf16x8_t*)(lds + (bufv)*32768 + lr_ * 128 + (koff0 ^ 64));   \
  }
#define LOAD_B(bufv, nh)                                                     \
  _Pragma("unroll") for (int n = 0; n < 2; n++) {                            \
    const int lr_ = (nh)*128 + wc * 32 + n * 16 + l15;                       \
    bfr[(nh)*2 + n][0] =                                                     \
        *(const bf16x8_t*)(lds + 65536 + (bufv)*32768 + lr_ * 128 + koff0);  \
    bfr[(nh)*2 + n][1] = *(const bf16x8_t*)(lds + 65536 + (bufv)*32768 +     \
                                            lr_ * 128 + (koff0 ^ 64));       \
  }
#define MMA(mh, nh)                                                          \
  __builtin_amdgcn_s_setprio(1);                                            \
  _Pragma("unroll") for (int m = 0; m < 4; m++)                              \
      _Pragma("unroll") for (int n = 0; n < 2; n++)                          \
          _Pragma("unroll") for (int kk = 0; kk < 2; kk++)                   \
              acc[(mh)*4 + m][(nh)*2 + n] =                                  \
      __builtin_amdgcn_mfma_f32_16x16x32_bf16(                               \
          af[m][kk], bfr[(nh)*2 + n][kk], acc[(mh)*4 + m][(nh)*2 + n], 0, 0, \
          0);                                                                \
  __builtin_amdgcn_s_setprio(0);

// body of the verified deep-ledger mainloop (prologue + NT tiles)
#define MAINLOOP(NTv)                                                        \
  STG_A(0, 0, 0); STG_B(0, 0, 0);                                            \
  STG_B(0, 1, 0); STG_A(0, 1, 0);                                            \
  STG_A(1, 0, 1); STG_B(1, 0, 1);                                            \
  STG_B(1, 1, 1); STG_A(1, 1, 1);                                            \
  VM12();                                                                    \
  SBAR();                                                                    \
  for (int t = 0; t < (NTv); ++t) {                                          \
    const int c = t & 1;                                                     \
    const int tn2 = (t + 2 < (NTv)) ? t + 2 : (NTv)-1;                       \
    LOAD_A(c, 0);                                                            \
    LOAD_B(c, 0);                                                            \
    SBAR();                                                                  \
    MMA(0, 0);                                                               \
    VM10();                                                                  \
    SBAR();                                                                  \
    LOAD_B(c, 1);                                                            \
    STG_A(c, 0, tn2);                                                        \
    STG_B(c, 0, tn2);                                                        \
    SBAR();                                                                  \
    MMA(0, 1);                                                               \
    VM12();                                                                  \
    SBAR();                                                                  \
    LOAD_A(c, 1);                                                            \
    STG_B(c, 1, tn2);                                                        \
    SBAR();                                                                  \
    MMA(1, 0);                                                               \
    SBAR();                                                                  \
    STG_A(c, 1, tn2);                                                        \
    VM12();                                                                  \
    SBAR();                                                                  \
    MMA(1, 1);                                                               \
    SBAR();                                                                  \
  }

// ---------------- gemm8<MODE>: 256x256, 8 waves, deep-ledger (verified) ------
// MODE 0: conv dual-role. roleA (swz<288): [theta;g] = [w1;w3] @ xT^T, bf16,
//         bias rows (bcat), split C0/C1. roleB: phiT = xT @ w2^T, bf16,
//         bias cols (b2) -> C2. K=1024.
// MODE 2: out = x + w4 @ yrT^T + b4, fp32. K=512.
// MODE 3: y = P' @ gT^T * (1/S), K=2304; 1/S computed in-epilogue from the
//         36 raw partial sums (stats) after a VM0+barrier LDS handover.
template <int MODE>
__global__ __launch_bounds__(512, 2) void gemm8(
    const u16* __restrict__ A, const u16* __restrict__ B,
    void* __restrict__ C0, void* __restrict__ C1, void* __restrict__ C2,
    const u16* __restrict__ W2, const float* __restrict__ bias,
    const float* __restrict__ bias2, const float* __restrict__ resid,
    const float* __restrict__ stats) {
  constexpr int LDA_ = (MODE == 0) ? 1024 : (MODE == 3) ? 2304 : 512;
  constexpr int LDB_ = (MODE == 0) ? 1024 : (MODE == 3) ? 2304 : 512;
  constexpr int KK = (MODE == 0) ? 1024 : (MODE == 3) ? 2304 : 512;
  constexpr int NT = KK >> 6;
  constexpr size_t AH = 64ull * LDA_ * 2, AC = 128ull * LDA_ * 2;
  constexpr size_t BH = 32ull * LDB_ * 2, BC = 128ull * LDB_ * 2;

  __shared__ alignas(16) char lds[131072];
  const int tid = threadIdx.x;
  const int w = tid >> 6, l = tid & 63;
  const int wr = w >> 2, wc = w & 3;
  const int l15 = l & 15, lhi = l >> 4;
  const int koff0 = (lhi * 16) ^ ((l & 7) << 4);

  unsigned bx, by, bz;
  bool roleB = false;
  if constexpr (MODE == 0) {
    unsigned bid = blockIdx.x;                      // 1D grid, 432 blocks
    unsigned swz = (bid & 7u) * 54u + (bid >> 3);   // XCD chunk = 54
    roleB = (swz >= 288u);
    unsigned s = roleB ? swz - 288u : swz;
    if (roleB) { bx = s % 2u; by = (s / 2u) % 9u; bz = s / 18u; }
    else       { bx = s % 9u; by = (s / 9u) % 4u; bz = s / 36u; }
  } else {
    const unsigned gx = gridDim.x, gy = gridDim.y;
    const unsigned nb = gx * gy * gridDim.z;
    unsigned bid = blockIdx.x + gx * (blockIdx.y + gy * blockIdx.z);
    bid = (bid & 7u) * (nb >> 3) + (bid >> 3);
    bx = bid % gx;
    unsigned t1 = bid / gx;
    by = t1 % gy;
    bz = t1 / gy;
  }
  const int rowbase = by * 256, colbase = bx * 256;

  const u16* Abase;
  const u16* Bbase;
  if constexpr (MODE == 0) {
    Abase = roleB ? (B + (size_t)bz * 2359296) : A;
    Bbase = roleB ? W2 : (B + (size_t)bz * 2359296);
  } else if constexpr (MODE == 3) {
    Abase = A + (size_t)bz * 5308416;
    Bbase = B + (size_t)bz * 1179648;
  } else {
    Abase = A;
    Bbase = B + (size_t)bz * 1179648;
  }

  const int sub = tid >> 3;
  const int kb = ((tid & 7) * 16) ^ ((sub & 7) << 4);
  const char* Ag = (const char*)(Abase + (size_t)(rowbase + sub) * LDA_) + kb;
  const char* Bg =
      (const char*)(Bbase + (size_t)(colbase + (sub >> 5) * 64 + (sub & 31)) *
                                LDB_) +
      kb;
  char* sAd = lds + w * 1024;
  char* sBd = lds + 65536 + w * 1024;

  f32x4_t acc[8][4] = {};
  bf16x8_t af[4][2], bfr[4][2];

  MAINLOOP(NT);

  if constexpr (MODE == 0) {
    if (!roleB) {
      const int rb = rowbase + wr * 128;
      const int which = rb >> 9;  // 0 -> theta, 1 -> g
      u16* Cp = (u16*)(which ? C1 : C0) + (size_t)bz * 1179648;
      const int rowout0 = rb - which * 512;
#pragma unroll
      for (int mf = 0; mf < 8; mf++)
#pragma unroll
        for (int r = 0; r < 4; r++) {
          const int ro = mf * 16 + lhi * 4 + r;
          const float bv = bias[rb + ro];
          const size_t rowo = (size_t)(rowout0 + ro) * 2304;
#pragma unroll
          for (int nf = 0; nf < 4; nf++) {
            const int col = colbase + wc * 64 + nf * 16 + l15;
            Cp[rowo + col] = f2bf(acc[mf][nf][r] + bv);
          }
        }
    } else {
      u16* Cp = (u16*)C2 + (size_t)bz * 1179648;
#pragma unroll
      for (int mf = 0; mf < 8; mf++)
#pragma unroll
        for (int r = 0; r < 4; r++) {
          const size_t rowo =
              (size_t)(rowbase + wr * 128 + mf * 16 + lhi * 4 + r) * 512;
#pragma unroll
          for (int nf = 0; nf < 4; nf++) {
            const int col = colbase + wc * 64 + nf * 16 + l15;
            Cp[rowo + col] = f2bf(acc[mf][nf][r] + bias2[col]);
          }
        }
    }
  } else if constexpr (MODE == 3) {
    // in-epilogue 1/S: LDS handover after all pending gload_lds land
    VM0();
    SBAR();
    float* rsum = (float*)lds;
    if (tid < 256) {
      const int row = rowbase + tid;
      float S = 0.f;
#pragma unroll 4
      for (int j = 0; j < 36; j++)
        S += stats[((size_t)bz * 36 + j) * 2304 + row];
      rsum[tid] = 1.0f / S;
    }
    LGKM0();
    SBAR();
    u16* Cp = (u16*)C0 + (size_t)bz * 1179648;
#pragma unroll
    for (int mf = 0; mf < 8; mf++)
#pragma unroll
      for (int r = 0; r < 4; r++) {
        const int ro = wr * 128 + mf * 16 + lhi * 4 + r;
        const float invs = rsum[ro];
        const int row = rowbase + ro;
#pragma unroll
        for (int nf = 0; nf < 4; nf++) {
          const int col = colbase + wc * 64 + nf * 16 + l15;
          Cp[(size_t)row * 512 + col] = f2bf(acc[mf][nf][r] * invs);
        }
      }
  } else {
    float* Cp = (float*)C0 + (size_t)bz * 2359296;
    const float* rp = resid + (size_t)bz * 2359296;
#pragma unroll
    for (int mf = 0; mf < 8; mf++)
#pragma unroll
      for (int r = 0; r < 4; r++) {
        const int row = rowbase + wr * 128 + mf * 16 + lhi * 4 + r;
        const float bv = bias[row];
#pragma unroll
        for (int nf = 0; nf < 4; nf++) {
          const int col = colbase + wc * 64 + nf * 16 + l15;
          Cp[(size_t)row * 2304 + col] =
              acc[mf][nf][r] + bv + rp[(size_t)row * 2304 + col];
        }
      }
  }
}

// ---------------- att_fused: att GEMM (648 blocks) + gT transpose (1152) -----
// blocks < 648: verified gemm8<1> body — att P' = bf16(exp(theta_v phi_v)),
// 36 partial row sums of the STORED values -> stats. K=512.
// blocks >= 648: gT[c][m] = (g_flat viewed [2304,512])^T, 2 64x64 tiles/block
// (g_nat relocated outside att's output window -> no ordering hazard).
__global__ __launch_bounds__(512, 2) void att_fused(
    const u16* __restrict__ A, const u16* __restrict__ B, u16* __restrict__ C0,
    float* __restrict__ stats, const u16* __restrict__ gn,
    u16* __restrict__ gTo) {
  constexpr int LDA_ = 512, LDB_ = 512, NT = 8;
  constexpr size_t AH = 64ull * 512 * 2, AC = 128ull * 512 * 2;
  constexpr size_t BH = 32ull * 512 * 2, BC = 128ull * 512 * 2;
  __shared__ alignas(16) char lds[131072];
  const int tid = threadIdx.x;

  if (blockIdx.x >= 648u) {
    // ---- gT transpose role ----
    const int t2 = (int)(blockIdx.x - 648u) * 2 + (tid >> 8);
    const int st = tid & 255;
    const int tx = st & 31, ty = st >> 5;
    const int xx = t2 & 7;
    const int rest = t2 >> 3;
    const int yy = rest % 36, b = rest / 36;
    const u16* in = gn + (size_t)b * 1179648;
    u16* out = gTo + (size_t)b * 1179648;
    const int c0 = xx * 64, r0 = yy * 64;
    u16* tt = (u16*)lds + (size_t)(tid >> 8) * 64 * 66;
#pragma unroll
    for (int i = 0; i < 64; i += 8) {
      unsigned v =
          *(const unsigned*)&in[(size_t)(r0 + ty + i) * 512 + c0 + 2 * tx];
      tt[(ty + i) * 66 + 2 * tx] = (u16)v;
      tt[(ty + i) * 66 + 2 * tx + 1] = (u16)(v >> 16);
    }
    __syncthreads();
#pragma unroll
    for (int i = 0; i < 64; i += 8) {
      unsigned lo = tt[(2 * tx) * 66 + ty + i];
      unsigned hi = tt[(2 * tx + 1) * 66 + ty + i];
      *(unsigned*)&out[(size_t)(c0 + ty + i) * 2304 + r0 + 2 * tx] =
          lo | (hi << 16);
    }
    return;
  }

  // ---- att GEMM role (verified body) ----
  const int w = tid >> 6, l = tid & 63;
  const int wr = w >> 2, wc = w & 3;
  const int l15 = l & 15, lhi = l >> 4;
  const int koff0 = (lhi * 16) ^ ((l & 7) << 4);

  unsigned bid = blockIdx.x;
  bid = (bid & 7u) * 81u + (bid >> 3);  // chunk 81 = one batch per XCD
  const unsigned bx = bid % 9u;
  const unsigned t1 = bid / 9u;
  const unsigned by = t1 % 9u;
  const unsigned bz = t1 / 9u;
  const int rowbase = by * 256, colbase = bx * 256;

  const u16* Abase = A + (size_t)bz * 1179648;
  const u16* Bbase = B + (size_t)bz * 1179648;

  const int sub = tid >> 3;
  const int kb = ((tid & 7) * 16) ^ ((sub & 7) << 4);
  const char* Ag = (const char*)(Abase + (size_t)(rowbase + sub) * LDA_) + kb;
  const char* Bg =
      (const char*)(Bbase + (size_t)(colbase + (sub >> 5) * 64 + (sub & 31)) *
                                LDB_) +
      kb;
  char* sAd = lds + w * 1024;
  char* sBd = lds + 65536 + w * 1024;

  f32x4_t acc[8][4] = {};
  bf16x8_t af[4][2], bfr[4][2];

  MAINLOOP(NT);

  u16* Cp = C0 + (size_t)bz * 5308416;
#pragma unroll
  for (int mf = 0; mf < 8; mf++)
#pragma unroll
    for (int r = 0; r < 4; r++) {
      const int row = rowbase + wr * 128 + mf * 16 + lhi * 4 + r;
      float sm = 0.f;
#pragma unroll
      for (int nf = 0; nf < 4; nf++) {
        const int col = colbase + wc * 64 + nf * 16 + l15;
        const u16 hb = f2bf(__expf(acc[mf][nf][r]));
        Cp[(size_t)row * 2304 + col] = hb;
        sm += bf2f(hb);  // sum of STORED values so S matches P' exactly
      }
#pragma unroll
      for (int mk = 1; mk < 16; mk <<= 1) sm += __shfl_xor(sm, mk);
      if (l15 == 0)
        stats[((size_t)bz * 36 + bx * 4 + wc) * 2304 + row] = sm;
    }
}

extern "C" void kernel_launch(void* const* d_in, const int* in_sizes, int n_in,
                              void* d_out, int out_size, void* d_ws,
                              size_t ws_size, hipStream_t stream) {
  const float* x = (const float*)d_in[0];
  const float* w1 = (const float*)d_in[1];
  const float* b1 = (const float*)d_in[2];
  const float* w2 = (const float*)d_in[3];
  const float* b2 = (const float*)d_in[4];
  const float* w3 = (const float*)d_in[5];
  const float* b3 = (const float*)d_in[6];
  const float* w4 = (const float*)d_in[7];
  const float* b4 = (const float*)d_in[8];
  float* out = (float*)d_out;
  char* ws = (char*)d_ws;

  // ws = 256 MiB:
  //  [0,84.93M)        att P' = bf16 exp(score); before att this window holds
  //                    xT(37.75M) | bcat(4K @56.6M) — both dead by att time.
  //  [84.93M,87.59M)   partial row sums 8*36*2304 f32
  //  [100M,118.9M)     g_nat (moved OUT of the att window so the gT-transpose
  //                    can run fused inside the att dispatch)
  //  [169.87M)         wb 4M | theta | phiT | gT | y | yrT (18.87M each)
  if (ws_size < 268435456ull) return;
  u16* p_xT = (u16*)(ws);
  float* p_bcat = (float*)(ws + 56623104);
  u16* p_att = (u16*)(ws);
  float* p_stats = (float*)(ws + 84934656);
  u16* p_gn = (u16*)(ws + 104857600);
  u16* p_wb = (u16*)(ws + 169869312);
  u16* p_theta = (u16*)(ws + 174063616);
  u16* p_phiT = (u16*)(ws + 192937984);
  u16* p_gT = (u16*)(ws + 211812352);
  u16* p_y = (u16*)(ws + 230686720);
  u16* p_yrT = (u16*)(ws + 249561088);

  // 1) fused prep: xT castT + weights cast [w1;w3;w2;w4] + bcat [b1;b3]
  prep_kernel<<<dim3(26628), 256, 0, stream>>>(x, w1, w3, w2, w4, b1, b3,
                                               p_xT, p_wb, p_bcat);
  // 2) conv dual-role: 288 blocks [theta;g] + 144 blocks phiT (432 total)
  gemm8<0><<<dim3(432), 512, 0, stream>>>(
      p_wb, p_xT, p_theta, p_gn, p_phiT, p_wb + 1048576, p_bcat, b2, nullptr,
      nullptr);
  // 3) att (648) + gT transpose (1152) fused: P' = bf16 exp(.) + partials;
  //    gT[c][m] = (g_flat viewed [2304,512])^T
  att_fused<<<dim3(1800), 512, 0, stream>>>(p_theta, p_phiT, p_att, p_stats,
                                            p_gn, p_gT);
  // 4) y = P' @ g_v * (1/S in-epilogue): 256^2 tiles, 144 blocks
  gemm8<3><<<dim3(2, 9, 8), 512, 0, stream>>>(
      p_att, p_gT, p_y, nullptr, nullptr, nullptr, nullptr, nullptr, nullptr,
      p_stats);
  // 5) yrT = (y_flat viewed [512,2304])^T
  transpose64<<<dim3(36, 8, 8), 256, 0, stream>>>(p_y, p_yrT, 512, 2304,
                                                  1179648L, 1179648L);
  // 6) out = x + w4 @ y_r + b4
  gemm8<2><<<dim3(9, 4, 8), 512, 0, stream>>>(
      p_wb + 1572864, p_yrT, out, nullptr, nullptr, nullptr, b4, nullptr, x,
      nullptr);
}

// Round 17
// 298.278 us; speedup vs baseline: 3.9075x; 1.0039x over previous
//
#include <hip/hip_runtime.h>

typedef unsigned short u16;
typedef __bf16 bf16x8_t __attribute__((ext_vector_type(8)));
typedef float f32x4_t __attribute__((ext_vector_type(4)));
typedef unsigned short u16x4_t __attribute__((ext_vector_type(4)));
typedef float f32x2_t __attribute__((ext_vector_type(2)));

__device__ __forceinline__ u16 f2bf(float f) {
  unsigned u = __builtin_bit_cast(unsigned, f);
  u += 0x7FFFu + ((u >> 16) & 1u);  // round-to-nearest-even
  return (u16)(u >> 16);
}
__device__ __forceinline__ float bf2f(u16 h) {
  unsigned u = ((unsigned)h) << 16;
  return __builtin_bit_cast(float, u);
}

typedef __attribute__((address_space(1))) const unsigned gas_u32;
typedef __attribute__((address_space(3))) unsigned las_u32;
__device__ __forceinline__ void gload16(const void* g, void* l) {
  __builtin_amdgcn_global_load_lds((gas_u32*)g, (las_u32*)l, 16, 0, 0);
}

#define SBAR()                                  \
  do {                                          \
    __builtin_amdgcn_sched_barrier(0);          \
    asm volatile("" ::: "memory");              \
    __builtin_amdgcn_s_barrier();               \
    asm volatile("" ::: "memory");              \
    __builtin_amdgcn_sched_barrier(0);          \
  } while (0)
#define VM0() asm volatile("s_waitcnt vmcnt(0)" ::: "memory")
#define VM10() asm volatile("s_waitcnt vmcnt(10)" ::: "memory")
#define VM12() asm volatile("s_waitcnt vmcnt(12)" ::: "memory")
#define LGKM0() asm volatile("s_waitcnt lgkmcnt(0)" ::: "memory")

// ---------------- fused prep (vectorized):
// xT castT 64x64 tiles (4608 blocks) | w cast float4 (2048) | bcat (1) -------
__global__ __launch_bounds__(256) void prep_kernel(
    const float* __restrict__ x, const float* __restrict__ w1,
    const float* __restrict__ w3, const float* __restrict__ w2,
    const float* __restrict__ w4, const float* __restrict__ b1,
    const float* __restrict__ b3, u16* __restrict__ xT, u16* __restrict__ wb,
    float* __restrict__ bcat) {
  const unsigned idx = blockIdx.x;
  const int tid = threadIdx.x;
  if (idx < 4608u) {
    // xT[b] = cast(x[b])^T : [1024,2304] -> [2304,1024], 64x64 tiles,
    // float2 reads + u32-packed writes (transpose64 pattern).
    __shared__ u16 t[64][66];
    const int cx = idx % 36, ry = (idx / 36) % 16, b = idx / 576;
    const float* in = x + (size_t)b * 2359296;
    u16* out = xT + (size_t)b * 2359296;
    const int c0 = cx * 64, r0 = ry * 64;
    const int tx = tid & 31, ty = tid >> 5;
#pragma unroll
    for (int i = 0; i < 64; i += 8) {
      f32x2_t v =
          *(const f32x2_t*)&in[(size_t)(r0 + ty + i) * 2304 + c0 + 2 * tx];
      t[ty + i][2 * tx] = f2bf(v[0]);
      t[ty + i][2 * tx + 1] = f2bf(v[1]);
    }
    __syncthreads();
#pragma unroll
    for (int i = 0; i < 64; i += 8) {
      unsigned lo = t[2 * tx][ty + i], hi = t[2 * tx + 1][ty + i];
      *(unsigned*)&out[(size_t)(c0 + ty + i) * 1024 + r0 + 2 * tx] =
          lo | (hi << 16);
    }
  } else if (idx < 6656u) {
    // weights -> bf16 as [w1; w3; w2; w4]; float4 read, 8B store
    const unsigned k = idx - 4608u;
    const size_t e = (size_t)k * 1024 + (size_t)tid * 4;  // global elem
    const int z = (int)(e >> 19);
    const int i = (int)(e & 524287u);
    const float* a = (z == 0) ? w1 : (z == 1) ? w3 : (z == 2) ? w2 : w4;
    f32x4_t v = *(const f32x4_t*)&a[i];
    u16x4_t o;
    o[0] = f2bf(v[0]); o[1] = f2bf(v[1]); o[2] = f2bf(v[2]); o[3] = f2bf(v[3]);
    *(u16x4_t*)&wb[(size_t)z * 524288 + i] = o;
  } else {
    const int i = tid * 4;
#pragma unroll
    for (int j = 0; j < 4; j++)
      bcat[i + j] = (i + j < 512) ? b1[i + j] : b3[i + j - 512];
  }
}

// ---------------- bf16 [R,C] -> [C,R], 64x64 tiles, u32-packed ---------------
__global__ __launch_bounds__(256) void transpose64(
    const u16* __restrict__ in, u16* __restrict__ out, int R, int C, long sIn,
    long sOut) {
  __shared__ u16 t[64][66];
  const int b = blockIdx.z;
  in += (long)b * sIn;
  out += (long)b * sOut;
  const int c0 = blockIdx.x * 64, r0 = blockIdx.y * 64;
  const int tx = threadIdx.x & 31, ty = threadIdx.x >> 5;
#pragma unroll
  for (int i = 0; i < 64; i += 8) {
    unsigned v = *(const unsigned*)&in[(long)(r0 + ty + i) * C + c0 + 2 * tx];
    t[ty + i][2 * tx] = (u16)v;
    t[ty + i][2 * tx + 1] = (u16)(v >> 16);
  }
  __syncthreads();
#pragma unroll
  for (int i = 0; i < 64; i += 8) {
    unsigned lo = t[2 * tx][ty + i], hi = t[2 * tx + 1][ty + i];
    *(unsigned*)&out[(long)(c0 + ty + i) * R + r0 + 2 * tx] = lo | (hi << 16);
  }
}

// ---------------- shared staging/fragment macros (8-phase 256^2 template) ----
#define STG_A(bufv, h, kt)                                          \
  do {                                                              \
    const char* g_ = Ag + (size_t)(kt) * 128 + (size_t)(h)*AH;      \
    char* d_ = sAd + (bufv)*32768 + (h)*16384;                      \
    gload16(g_, d_);                                                \
    gload16(g_ + AC, d_ + 8192);                                    \
  } while (0)
#define STG_B(bufv, h, kt)                                          \
  do {                                                              \
    const char* g_ = Bg + (size_t)(kt) * 128 + (size_t)(h)*BH;      \
    char* d_ = sBd + (bufv)*32768 + (h)*16384;                      \
    gload16(g_, d_);                                                \
    gload16(g_ + BC, d_ + 8192);                                    \
  } while (0)
#define LOAD_A(bufv, mh)                                                     \
  _Pragma("unroll") for (int m = 0; m < 4; m++) {                            \
    const int lr_ = (mh)*128 + wr * 64 + m * 16 + l15;                       \
    af[m][0] = *(const bf16x8_t*)(lds + (bufv)*32768 + lr_ * 128 + koff0);   \
    af[m][1] =                                                               \
        *(const bf16x8_t*)(lds + (bufv)*32768 + lr_ * 128 + (koff0 ^ 64));   \
  }
#define LOAD_B(bufv, nh)                                                     \
  _Pragma("unroll") for (int n = 0; n < 2; n++) {                            \
    const int lr_ = (nh)*128 + wc * 32 + n * 16 + l15;                       \
    bfr[(nh)*2 + n][0] =                                                     \
        *(const bf16x8_t*)(lds + 65536 + (bufv)*32768 + lr_ * 128 + koff0);  \
    bfr[(nh)*2 + n][1] = *(const bf16x8_t*)(lds + 65536 + (bufv)*32768 +     \
                                            lr_ * 128 + (koff0 ^ 64));       \
  }
#define MMA(mh, nh)                                                          \
  __builtin_amdgcn_s_setprio(1);                                            \
  _Pragma("unroll") for (int m = 0; m < 4; m++)                              \
      _Pragma("unroll") for (int n = 0; n < 2; n++)                          \
          _Pragma("unroll") for (int kk = 0; kk < 2; kk++)                   \
              acc[(mh)*4 + m][(nh)*2 + n] =                                  \
      __builtin_amdgcn_mfma_f32_16x16x32_bf16(                               \
          af[m][kk], bfr[(nh)*2 + n][kk], acc[(mh)*4 + m][(nh)*2 + n], 0, 0, \
          0);                                                                \
  __builtin_amdgcn_s_setprio(0);

// body of the verified deep-ledger mainloop (prologue + NT tiles)
#define MAINLOOP(NTv)                                                        \
  STG_A(0, 0, 0); STG_B(0, 0, 0);                                            \
  STG_B(0, 1, 0); STG_A(0, 1, 0);                                            \
  STG_A(1, 0, 1); STG_B(1, 0, 1);                                            \
  STG_B(1, 1, 1); STG_A(1, 1, 1);                                            \
  VM12();                                                                    \
  SBAR();                                                                    \
  for (int t = 0; t < (NTv); ++t) {                                          \
    const int c = t & 1;                                                     \
    const int tn2 = (t + 2 < (NTv)) ? t + 2 : (NTv)-1;                       \
    LOAD_A(c, 0);                                                            \
    LOAD_B(c, 0);                                                            \
    SBAR();                                                                  \
    MMA(0, 0);                                                               \
    VM10();                                                                  \
    SBAR();                                                                  \
    LOAD_B(c, 1);                                                            \
    STG_A(c, 0, tn2);                                                        \
    STG_B(c, 0, tn2);                                                        \
    SBAR();                                                                  \
    MMA(0, 1);                                                               \
    VM12();                                                                  \
    SBAR();                                                                  \
    LOAD_A(c, 1);                                                            \
    STG_B(c, 1, tn2);                                                        \
    SBAR();                                                                  \
    MMA(1, 0);                                                               \
    SBAR();                                                                  \
    STG_A(c, 1, tn2);                                                        \
    VM12();                                                                  \
    SBAR();                                                                  \
    MMA(1, 1);                                                               \
    SBAR();                                                                  \
  }

// ---------------- gemm8<MODE>: 256x256, 8 waves, deep-ledger (verified) ------
// MODE 0: conv dual-role. roleA (swz<288): [theta;g] = [w1;w3] @ xT^T, bf16,
//         bias rows (bcat), split C0/C1. roleB: phiT = xT @ w2^T, bf16,
//         bias cols (b2) -> C2. K=1024.
// MODE 2: out = x + w4 @ yrT^T + b4, fp32. K=512.
// MODE 3: y = P' @ gT^T * (1/S), K=2304; 1/S computed in-epilogue from the
//         36 raw partial sums (stats) after a VM0+barrier LDS handover.
template <int MODE>
__global__ __launch_bounds__(512, 2) void gemm8(
    const u16* __restrict__ A, const u16* __restrict__ B,
    void* __restrict__ C0, void* __restrict__ C1, void* __restrict__ C2,
    const u16* __restrict__ W2, const float* __restrict__ bias,
    const float* __restrict__ bias2, const float* __restrict__ resid,
    const float* __restrict__ stats) {
  constexpr int LDA_ = (MODE == 0) ? 1024 : (MODE == 3) ? 2304 : 512;
  constexpr int LDB_ = (MODE == 0) ? 1024 : (MODE == 3) ? 2304 : 512;
  constexpr int KK = (MODE == 0) ? 1024 : (MODE == 3) ? 2304 : 512;
  constexpr int NT = KK >> 6;
  constexpr size_t AH = 64ull * LDA_ * 2, AC = 128ull * LDA_ * 2;
  constexpr size_t BH = 32ull * LDB_ * 2, BC = 128ull * LDB_ * 2;

  __shared__ alignas(16) char lds[131072];
  const int tid = threadIdx.x;
  const int w = tid >> 6, l = tid & 63;
  const int wr = w >> 2, wc = w & 3;
  const int l15 = l & 15, lhi = l >> 4;
  const int koff0 = (lhi * 16) ^ ((l & 7) << 4);

  unsigned bx, by, bz;
  bool roleB = false;
  if constexpr (MODE == 0) {
    unsigned bid = blockIdx.x;                      // 1D grid, 432 blocks
    unsigned swz = (bid & 7u) * 54u + (bid >> 3);   // XCD chunk = 54
    roleB = (swz >= 288u);
    unsigned s = roleB ? swz - 288u : swz;
    if (roleB) { bx = s % 2u; by = (s / 2u) % 9u; bz = s / 18u; }
    else       { bx = s % 9u; by = (s / 9u) % 4u; bz = s / 36u; }
  } else {
    const unsigned gx = gridDim.x, gy = gridDim.y;
    const unsigned nb = gx * gy * gridDim.z;
    unsigned bid = blockIdx.x + gx * (blockIdx.y + gy * blockIdx.z);
    bid = (bid & 7u) * (nb >> 3) + (bid >> 3);
    bx = bid % gx;
    unsigned t1 = bid / gx;
    by = t1 % gy;
    bz = t1 / gy;
  }
  const int rowbase = by * 256, colbase = bx * 256;

  const u16* Abase;
  const u16* Bbase;
  if constexpr (MODE == 0) {
    Abase = roleB ? (B + (size_t)bz * 2359296) : A;
    Bbase = roleB ? W2 : (B + (size_t)bz * 2359296);
  } else if constexpr (MODE == 3) {
    Abase = A + (size_t)bz * 5308416;
    Bbase = B + (size_t)bz * 1179648;
  } else {
    Abase = A;
    Bbase = B + (size_t)bz * 1179648;
  }

  const int sub = tid >> 3;
  const int kb = ((tid & 7) * 16) ^ ((sub & 7) << 4);
  const char* Ag = (const char*)(Abase + (size_t)(rowbase + sub) * LDA_) + kb;
  const char* Bg =
      (const char*)(Bbase + (size_t)(colbase + (sub >> 5) * 64 + (sub & 31)) *
                                LDB_) +
      kb;
  char* sAd = lds + w * 1024;
  char* sBd = lds + 65536 + w * 1024;

  f32x4_t acc[8][4] = {};
  bf16x8_t af[4][2], bfr[4][2];

  MAINLOOP(NT);

  if constexpr (MODE == 0) {
    if (!roleB) {
      const int rb = rowbase + wr * 128;
      const int which = rb >> 9;  // 0 -> theta, 1 -> g
      u16* Cp = (u16*)(which ? C1 : C0) + (size_t)bz * 1179648;
      const int rowout0 = rb - which * 512;
#pragma unroll
      for (int mf = 0; mf < 8; mf++)
#pragma unroll
        for (int r = 0; r < 4; r++) {
          const int ro = mf * 16 + lhi * 4 + r;
          const float bv = bias[rb + ro];
          const size_t rowo = (size_t)(rowout0 + ro) * 2304;
#pragma unroll
          for (int nf = 0; nf < 4; nf++) {
            const int col = colbase + wc * 64 + nf * 16 + l15;
            Cp[rowo + col] = f2bf(acc[mf][nf][r] + bv);
          }
        }
    } else {
      u16* Cp = (u16*)C2 + (size_t)bz * 1179648;
#pragma unroll
      for (int mf = 0; mf < 8; mf++)
#pragma unroll
        for (int r = 0; r < 4; r++) {
          const size_t rowo =
              (size_t)(rowbase + wr * 128 + mf * 16 + lhi * 4 + r) * 512;
#pragma unroll
          for (int nf = 0; nf < 4; nf++) {
            const int col = colbase + wc * 64 + nf * 16 + l15;
            Cp[rowo + col] = f2bf(acc[mf][nf][r] + bias2[col]);
          }
        }
    }
  } else if constexpr (MODE == 3) {
    // in-epilogue 1/S: LDS handover after all pending gload_lds land
    VM0();
    SBAR();
    float* rsum = (float*)lds;
    if (tid < 256) {
      const int row = rowbase + tid;
      float S = 0.f;
#pragma unroll 4
      for (int j = 0; j < 36; j++)
        S += stats[((size_t)bz * 36 + j) * 2304 + row];
      rsum[tid] = 1.0f / S;
    }
    LGKM0();
    SBAR();
    u16* Cp = (u16*)C0 + (size_t)bz * 1179648;
#pragma unroll
    for (int mf = 0; mf < 8; mf++)
#pragma unroll
      for (int r = 0; r < 4; r++) {
        const int ro = wr * 128 + mf * 16 + lhi * 4 + r;
        const float invs = rsum[ro];
        const int row = rowbase + ro;
#pragma unroll
        for (int nf = 0; nf < 4; nf++) {
          const int col = colbase + wc * 64 + nf * 16 + l15;
          Cp[(size_t)row * 512 + col] = f2bf(acc[mf][nf][r] * invs);
        }
      }
  } else {
    float* Cp = (float*)C0 + (size_t)bz * 2359296;
    const float* rp = resid + (size_t)bz * 2359296;
#pragma unroll
    for (int mf = 0; mf < 8; mf++)
#pragma unroll
      for (int r = 0; r < 4; r++) {
        const int row = rowbase + wr * 128 + mf * 16 + lhi * 4 + r;
        const float bv = bias[row];
#pragma unroll
        for (int nf = 0; nf < 4; nf++) {
          const int col = colbase + wc * 64 + nf * 16 + l15;
          Cp[(size_t)row * 2304 + col] =
              acc[mf][nf][r] + bv + rp[(size_t)row * 2304 + col];
        }
      }
  }
}

// ---------------- att_fused: att GEMM (648 blocks) + gT transpose (1152) -----
// blocks < 648: verified gemm8<1> body — att P' = bf16(exp(theta_v phi_v)),
// 36 partial row sums of the STORED values -> stats. K=512.
// blocks >= 648: gT[c][m] = (g_flat viewed [2304,512])^T, 2 64x64 tiles/block
// (g_nat relocated outside att's output window -> no ordering hazard).
__global__ __launch_bounds__(512, 2) void att_fused(
    const u16* __restrict__ A, const u16* __restrict__ B, u16* __restrict__ C0,
    float* __restrict__ stats, const u16* __restrict__ gn,
    u16* __restrict__ gTo) {
  constexpr int LDA_ = 512, LDB_ = 512, NT = 8;
  constexpr size_t AH = 64ull * 512 * 2, AC = 128ull * 512 * 2;
  constexpr size_t BH = 32ull * 512 * 2, BC = 128ull * 512 * 2;
  __shared__ alignas(16) char lds[131072];
  const int tid = threadIdx.x;

  if (blockIdx.x >= 648u) {
    // ---- gT transpose role ----
    const int t2 = (int)(blockIdx.x - 648u) * 2 + (tid >> 8);
    const int st = tid & 255;
    const int tx = st & 31, ty = st >> 5;
    const int xx = t2 & 7;
    const int rest = t2 >> 3;
    const int yy = rest % 36, b = rest / 36;
    const u16* in = gn + (size_t)b * 1179648;
    u16* out = gTo + (size_t)b * 1179648;
    const int c0 = xx * 64, r0 = yy * 64;
    u16* tt = (u16*)lds + (size_t)(tid >> 8) * 64 * 66;
#pragma unroll
    for (int i = 0; i < 64; i += 8) {
      unsigned v =
          *(const unsigned*)&in[(size_t)(r0 + ty + i) * 512 + c0 + 2 * tx];
      tt[(ty + i) * 66 + 2 * tx] = (u16)v;
      tt[(ty + i) * 66 + 2 * tx + 1] = (u16)(v >> 16);
    }
    __syncthreads();
#pragma unroll
    for (int i = 0; i < 64; i += 8) {
      unsigned lo = tt[(2 * tx) * 66 + ty + i];
      unsigned hi = tt[(2 * tx + 1) * 66 + ty + i];
      *(unsigned*)&out[(size_t)(c0 + ty + i) * 2304 + r0 + 2 * tx] =
          lo | (hi << 16);
    }
    return;
  }

  // ---- att GEMM role (verified body) ----
  const int w = tid >> 6, l = tid & 63;
  const int wr = w >> 2, wc = w & 3;
  const int l15 = l & 15, lhi = l >> 4;
  const int koff0 = (lhi * 16) ^ ((l & 7) << 4);

  unsigned bid = blockIdx.x;
  bid = (bid & 7u) * 81u + (bid >> 3);  // chunk 81 = one batch per XCD
  const unsigned bx = bid % 9u;
  const unsigned t1 = bid / 9u;
  const unsigned by = t1 % 9u;
  const unsigned bz = t1 / 9u;
  const int rowbase = by * 256, colbase = bx * 256;

  const u16* Abase = A + (size_t)bz * 1179648;
  const u16* Bbase = B + (size_t)bz * 1179648;

  const int sub = tid >> 3;
  const int kb = ((tid & 7) * 16) ^ ((sub & 7) << 4);
  const char* Ag = (const char*)(Abase + (size_t)(rowbase + sub) * LDA_) + kb;
  const char* Bg =
      (const char*)(Bbase + (size_t)(colbase + (sub >> 5) * 64 + (sub & 31)) *
                                LDB_) +
      kb;
  char* sAd = lds + w * 1024;
  char* sBd = lds + 65536 + w * 1024;

  f32x4_t acc[8][4] = {};
  bf16x8_t af[4][2], bfr[4][2];

  MAINLOOP(NT);

  u16* Cp = C0 + (size_t)bz * 5308416;
#pragma unroll
  for (int mf = 0; mf < 8; mf++)
#pragma unroll
    for (int r = 0; r < 4; r++) {
      const int row = rowbase + wr * 128 + mf * 16 + lhi * 4 + r;
      float sm = 0.f;
#pragma unroll
      for (int nf = 0; nf < 4; nf++) {
        const int col = colbase + wc * 64 + nf * 16 + l15;
        const u16 hb = f2bf(__expf(acc[mf][nf][r]));
        Cp[(size_t)row * 2304 + col] = hb;
        sm += bf2f(hb);  // sum of STORED values so S matches P' exactly
      }
#pragma unroll
      for (int mk = 1; mk < 16; mk <<= 1) sm += __shfl_xor(sm, mk);
      if (l15 == 0)
        stats[((size_t)bz * 36 + bx * 4 + wc) * 2304 + row] = sm;
    }
}

extern "C" void kernel_launch(void* const* d_in, const int* in_sizes, int n_in,
                              void* d_out, int out_size, void* d_ws,
                              size_t ws_size, hipStream_t stream) {
  const float* x = (const float*)d_in[0];
  const float* w1 = (const float*)d_in[1];
  const float* b1 = (const float*)d_in[2];
  const float* w2 = (const float*)d_in[3];
  const float* b2 = (const float*)d_in[4];
  const float* w3 = (const float*)d_in[5];
  const float* b3 = (const float*)d_in[6];
  const float* w4 = (const float*)d_in[7];
  const float* b4 = (const float*)d_in[8];
  float* out = (float*)d_out;
  char* ws = (char*)d_ws;

  // ws = 256 MiB:
  //  [0,84.93M)        att P' = bf16 exp(score); before att this window holds
  //                    xT(37.75M) | bcat(4K @56.6M) — both dead by att time.
  //  [84.93M,87.59M)   partial row sums 8*36*2304 f32
  //  [100M,118.9M)     g_nat (outside the att window so the gT-transpose can
  //                    run fused inside the att dispatch)
  //  [169.87M)         wb 4M | theta | phiT | gT | y | yrT (18.87M each)
  if (ws_size < 268435456ull) return;
  u16* p_xT = (u16*)(ws);
  float* p_bcat = (float*)(ws + 56623104);
  u16* p_att = (u16*)(ws);
  float* p_stats = (float*)(ws + 84934656);
  u16* p_gn = (u16*)(ws + 104857600);
  u16* p_wb = (u16*)(ws + 169869312);
  u16* p_theta = (u16*)(ws + 174063616);
  u16* p_phiT = (u16*)(ws + 192937984);
  u16* p_gT = (u16*)(ws + 211812352);
  u16* p_y = (u16*)(ws + 230686720);
  u16* p_yrT = (u16*)(ws + 249561088);

  // 1) fused prep (vectorized): xT castT + weights cast + bcat
  prep_kernel<<<dim3(6657), 256, 0, stream>>>(x, w1, w3, w2, w4, b1, b3,
                                              p_xT, p_wb, p_bcat);
  // 2) conv dual-role: 288 blocks [theta;g] + 144 blocks phiT (432 total)
  gemm8<0><<<dim3(432), 512, 0, stream>>>(
      p_wb, p_xT, p_theta, p_gn, p_phiT, p_wb + 1048576, p_bcat, b2, nullptr,
      nullptr);
  // 3) att (648) + gT transpose (1152) fused
  att_fused<<<dim3(1800), 512, 0, stream>>>(p_theta, p_phiT, p_att, p_stats,
                                            p_gn, p_gT);
  // 4) y = P' @ g_v * (1/S in-epilogue): 256^2 tiles, 144 blocks
  gemm8<3><<<dim3(2, 9, 8), 512, 0, stream>>>(
      p_att, p_gT, p_y, nullptr, nullptr, nullptr, nullptr, nullptr, nullptr,
      p_stats);
  // 5) yrT = (y_flat viewed [512,2304])^T
  transpose64<<<dim3(36, 8, 8), 256, 0, stream>>>(p_y, p_yrT, 512, 2304,
                                                  1179648L, 1179648L);
  // 6) out = x + w4 @ y_r + b4
  gemm8<2><<<dim3(9, 4, 8), 512, 0, stream>>>(
      p_wb + 1572864, p_yrT, out, nullptr, nullptr, nullptr, b4, nullptr, x,
      nullptr);
}